// Round 1
// baseline (265.223 us; speedup 1.0000x reference)
//
#include <hip/hip_runtime.h>

typedef __bf16 bf16x8 __attribute__((ext_vector_type(8)));
typedef float floatx4 __attribute__((ext_vector_type(4)));

#define DEVI __device__ __forceinline__

DEVI unsigned short f2bf(float f) {
  union { float f; unsigned u; } v; v.f = f;
  unsigned r = v.u + 0x7FFFu + ((v.u >> 16) & 1u);
  return (unsigned short)(r >> 16);
}

DEVI void gload_lds16(const void* g, void* l) {
  __builtin_amdgcn_global_load_lds((const __attribute__((address_space(1))) void*)g,
                                   (__attribute__((address_space(3))) void*)l,
                                   16, 0, 0);
}

// ---------------- weight prep: pack phi/g into [512,512] bf16, theta [256,512], Ww [512,256], biases ----
__global__ __launch_bounds__(256) void k_prep(
    const float* __restrict__ phi_w, const float* __restrict__ g_w,
    const float* __restrict__ theta_w, const float* __restrict__ W_w,
    const float* __restrict__ phi_b, const float* __restrict__ g_b,
    unsigned short* __restrict__ wpg, unsigned short* __restrict__ thw,
    unsigned short* __restrict__ ww, float* __restrict__ pgbias) {
  const int T0 = 512 * 512, T1 = T0 + 256 * 512, T2 = T1 + 512 * 256, T3 = T2 + 512;
  for (int i = blockIdx.x * 256 + threadIdx.x; i < T3; i += gridDim.x * 256) {
    if (i < T0) {
      int o = i >> 9, c = i & 511;
      float v = (o < 256) ? phi_w[o * 512 + c] : g_w[(o - 256) * 512 + c];
      wpg[i] = f2bf(v);
    } else if (i < T1) {
      int j = i - T0; thw[j] = f2bf(theta_w[j]);
    } else if (i < T2) {
      int j = i - T1; ww[j] = f2bf(W_w[j]);
    } else {
      int o = i - T2; pgbias[o] = (o < 256) ? phi_b[o] : g_b[o - 256];
    }
  }
}

// ---------------- transpose-convert: x[B,512,2048] f32 -> xt[B,2048,512] bf16 ----------------
__global__ __launch_bounds__(256) void k_transpose(const float* __restrict__ x,
                                                   unsigned short* __restrict__ xt) {
  __shared__ float tile[64][65];
  const int b = blockIdx.z, c0 = blockIdx.y * 64, n0 = blockIdx.x * 64;
  const int t = threadIdx.x;
  const float* xb = x + (size_t)b * 512 * 2048;
#pragma unroll
  for (int i = 0; i < 16; ++i) {
    int lin = i * 256 + t;
    int lc = lin >> 6, ln = lin & 63;
    tile[lc][ln] = xb[(size_t)(c0 + lc) * 2048 + (n0 + ln)];
  }
  __syncthreads();
  unsigned short* xtb = xt + (size_t)b * 2048 * 512;
#pragma unroll
  for (int i = 0; i < 16; ++i) {
    int lin = i * 256 + t;
    int ln = lin >> 6, lc = lin & 63;
    xtb[(size_t)(n0 + ln) * 512 + (c0 + lc)] = f2bf(tile[lc][ln]);
  }
}

// ---------------- GEMM  C[i,j] = scale * sum_k A[i,k]*B[j,k] (+bias) ; A:[M,K] B:[N,K] bf16 row-major ----
// EPI: 0 = none, 1 = +bias[row], 2 = +bias[col].  Output bf16 [M,N].
template <int BM, int BN, int EPI>
__global__ __launch_bounds__(256) void k_gemm_abt(
    const unsigned short* __restrict__ A, const unsigned short* __restrict__ B,
    unsigned short* __restrict__ C, int M, int N, int K,
    size_t sA, size_t sB, size_t sC,
    const float* __restrict__ bias, float scale) {
  constexpr int WM = BM / 2, WN = BN / 2;
  constexpr int FM = WM / 16, FN = WN / 16;
  __shared__ __align__(16) __bf16 At[BM * 32];
  __shared__ __align__(16) __bf16 Bt[BN * 32];
  const int t = threadIdx.x;
  const int z = blockIdx.z;
  const int row0 = blockIdx.y * BM;
  const int col0 = blockIdx.x * BN;
  const unsigned short* Az = A + (size_t)z * sA;
  const unsigned short* Bz = B + (size_t)z * sB;
  unsigned short* Cz = C + (size_t)z * sC;

  const int w = t >> 6, lane = t & 63;
  const int l16 = lane & 15, lq = lane >> 4;
  const int wrow0 = (w >> 1) * WM, wcol0 = (w & 1) * WN;

  floatx4 acc[FM][FN];
#pragma unroll
  for (int m = 0; m < FM; ++m)
#pragma unroll
    for (int n = 0; n < FN; ++n) acc[m][n] = (floatx4){0.f, 0.f, 0.f, 0.f};

  const int kt_end = K >> 5;
  for (int kt = 0; kt < kt_end; ++kt) {
    __syncthreads();
    // stage A tile [BM][32] bf16 : BM*4 chunks of 16B, linear in LDS
#pragma unroll
    for (int i = 0; i < BM * 4 / 256; ++i) {
      int ch = i * 256 + t;
      int r = ch >> 2, kq = ch & 3;
      gload_lds16(Az + (size_t)(row0 + r) * K + (kt << 5) + (kq << 3), &At[ch * 8]);
    }
#pragma unroll
    for (int i = 0; i < BN * 4 / 256; ++i) {
      int ch = i * 256 + t;
      int r = ch >> 2, kq = ch & 3;
      gload_lds16(Bz + (size_t)(col0 + r) * K + (kt << 5) + (kq << 3), &Bt[ch * 8]);
    }
    __syncthreads();

    bf16x8 af[FM], bq[FN];
#pragma unroll
    for (int m = 0; m < FM; ++m)
      af[m] = *(const bf16x8*)&At[(wrow0 + m * 16 + l16) * 32 + lq * 8];
#pragma unroll
    for (int n = 0; n < FN; ++n)
      bq[n] = *(const bf16x8*)&Bt[(wcol0 + n * 16 + l16) * 32 + lq * 8];
#pragma unroll
    for (int m = 0; m < FM; ++m)
#pragma unroll
      for (int n = 0; n < FN; ++n)
        acc[m][n] = __builtin_amdgcn_mfma_f32_16x16x32_bf16(af[m], bq[n], acc[m][n], 0, 0, 0);
  }

#pragma unroll
  for (int m = 0; m < FM; ++m)
#pragma unroll
    for (int n = 0; n < FN; ++n)
#pragma unroll
      for (int r = 0; r < 4; ++r) {
        int gr = row0 + wrow0 + m * 16 + lq * 4 + r;
        int gc = col0 + wcol0 + n * 16 + l16;
        float v = acc[m][n][r] * scale;
        if (EPI == 1) v += bias[gr];
        if (EPI == 2) v += bias[gc];
        Cz[(size_t)gr * N + gc] = f2bf(v);
      }
}

// ---------------- BN stats: per channel c, mean/var over (B,N); emit scale/shift -------------
__global__ __launch_bounds__(256) void k_bnstats(const unsigned short* __restrict__ w,
                                                 const float* __restrict__ gamma,
                                                 const float* __restrict__ beta,
                                                 float* __restrict__ scale,
                                                 float* __restrict__ shift) {
  const int c = blockIdx.x, t = threadIdx.x;
  float s = 0.f, ss = 0.f;
  for (int b = 0; b < 16; ++b) {
    const unsigned short* p = w + ((size_t)b * 512 + c) * 2048 + t * 8;
    uint4 v = *(const uint4*)p;
    unsigned u[4] = {v.x, v.y, v.z, v.w};
#pragma unroll
    for (int j = 0; j < 4; ++j) {
      union { unsigned q; float f; } a, bb;
      a.q = u[j] << 16;
      bb.q = u[j] & 0xFFFF0000u;
      s += a.f + bb.f;
      ss += a.f * a.f + bb.f * bb.f;
    }
  }
#pragma unroll
  for (int off = 32; off; off >>= 1) {
    s += __shfl_down(s, off);
    ss += __shfl_down(ss, off);
  }
  __shared__ float ls[4], lss[4];
  if ((t & 63) == 0) { ls[t >> 6] = s; lss[t >> 6] = ss; }
  __syncthreads();
  if (t == 0) {
    float S = ls[0] + ls[1] + ls[2] + ls[3];
    float SS = lss[0] + lss[1] + lss[2] + lss[3];
    const float inv = 1.f / 32768.f;
    float mean = S * inv;
    float var = SS * inv - mean * mean;
    float rs = rsqrtf(var + 1e-5f);
    float sc = gamma[c] * rs;
    scale[c] = sc;
    shift[c] = beta[c] - mean * sc;
  }
}

// ---------------- finalize: out = w*scale[c] + shift[c] + x ----------------
__global__ __launch_bounds__(256) void k_final(const unsigned short* __restrict__ w,
                                               const float* __restrict__ x,
                                               const float* __restrict__ scale,
                                               const float* __restrict__ shift,
                                               float* __restrict__ out) {
  const size_t total4 = (size_t)16 * 512 * 2048 / 4;
  size_t stride = (size_t)gridDim.x * 256;
  for (size_t i = (size_t)blockIdx.x * 256 + threadIdx.x; i < total4; i += stride) {
    size_t e = i * 4;
    int c = (int)((e >> 11) & 511);
    float sc = scale[c], sh = shift[c];
    uint2 wv = *(const uint2*)(w + e);
    float4 xv = *(const float4*)(x + e);
    float4 o;
    union { unsigned q; float f; } a;
    a.q = wv.x << 16;          o.x = a.f * sc + sh + xv.x;
    a.q = wv.x & 0xFFFF0000u;  o.y = a.f * sc + sh + xv.y;
    a.q = wv.y << 16;          o.z = a.f * sc + sh + xv.z;
    a.q = wv.y & 0xFFFF0000u;  o.w = a.f * sc + sh + xv.w;
    *(float4*)(out + e) = o;
  }
}

extern "C" void kernel_launch(void* const* d_in, const int* in_sizes, int n_in,
                              void* d_out, int out_size, void* d_ws, size_t ws_size,
                              hipStream_t stream) {
  const float* x       = (const float*)d_in[0];
  const float* theta_w = (const float*)d_in[1];
  const float* theta_b = (const float*)d_in[2];
  const float* phi_w   = (const float*)d_in[3];
  const float* phi_b   = (const float*)d_in[4];
  const float* g_w     = (const float*)d_in[5];
  const float* g_b     = (const float*)d_in[6];
  const float* W_w     = (const float*)d_in[7];
  const float* W_b     = (const float*)d_in[8];
  const float* gamma   = (const float*)d_in[9];
  const float* beta    = (const float*)d_in[10];
  float* out = (float*)d_out;

  // B=16, C=512, Ch=256, N=2048
  char* ws = (char*)d_ws;
  size_t off = 0;
  auto alloc = [&](size_t bytes) {
    char* p = ws + off;
    off = (off + bytes + 255) & ~(size_t)255;
    return p;
  };
  unsigned short* xt    = (unsigned short*)alloc((size_t)16 * 2048 * 512 * 2);  // x^T bf16 [B,N,C]
  unsigned short* phg   = (unsigned short*)alloc((size_t)16 * 512 * 2048 * 2);  // [B,512(ph|g),N]
  unsigned short* tht   = (unsigned short*)alloc((size_t)16 * 2048 * 256 * 2);  // [B,N,Ch]
  unsigned short* amat  = (unsigned short*)alloc((size_t)16 * 256 * 256 * 2);   // K'[c',c] per batch
  unsigned short* mmat  = (unsigned short*)alloc((size_t)16 * 512 * 256 * 2);   // M per batch
  unsigned short* wbuf  = (unsigned short*)alloc((size_t)16 * 512 * 2048 * 2);  // w bf16 [B,C,N]
  unsigned short* wpg   = (unsigned short*)alloc((size_t)512 * 512 * 2);
  unsigned short* thw   = (unsigned short*)alloc((size_t)256 * 512 * 2);
  unsigned short* ww    = (unsigned short*)alloc((size_t)512 * 256 * 2);
  float* pgbias         = (float*)alloc(512 * 4);
  float* scale          = (float*)alloc(512 * 4);
  float* shift          = (float*)alloc(512 * 4);
  (void)ws_size; (void)in_sizes; (void)n_in; (void)out_size;

  const size_t sXT = (size_t)2048 * 512;   // per-batch elements of xt
  const size_t sPG = (size_t)512 * 2048;
  const size_t sTH = (size_t)2048 * 256;
  const size_t sAM = (size_t)256 * 256;
  const size_t sMM = (size_t)512 * 256;
  const size_t sW  = (size_t)512 * 2048;

  k_prep<<<1024, 256, 0, stream>>>(phi_w, g_w, theta_w, W_w, phi_b, g_b, wpg, thw, ww, pgbias);
  k_transpose<<<dim3(32, 8, 16), 256, 0, stream>>>(x, xt);

  // PhG[o,n] = sum_c Wpg[o,c] xt[n,c] + pgbias[o]
  k_gemm_abt<128, 128, 1><<<dim3(16, 4, 16), 256, 0, stream>>>(
      wpg, xt, phg, 512, 2048, 512, 0, sXT, sPG, pgbias, 1.f);
  // tht[n,o] = sum_c xt[n,c] theta_w[o,c] + theta_b[o]
  k_gemm_abt<128, 128, 2><<<dim3(2, 16, 16), 256, 0, stream>>>(
      xt, thw, tht, 2048, 256, 512, sXT, 0, sTH, theta_b, 1.f);
  // amat[c',c] = sum_n Ph[c',n] G[c,n]
  k_gemm_abt<64, 64, 0><<<dim3(4, 4, 16), 256, 0, stream>>>(
      phg, phg + (size_t)256 * 2048, amat, 256, 256, 2048, sPG, sPG, sAM, nullptr, 1.f);
  // mmat[co,c'] = (1/N) sum_c Ww[co,c] amat[c',c]
  k_gemm_abt<64, 64, 0><<<dim3(4, 8, 16), 256, 0, stream>>>(
      ww, amat, mmat, 512, 256, 256, 0, sAM, sMM, nullptr, 1.f / 2048.f);
  // w[co,n] = sum_c' mmat[co,c'] tht[n,c'] + W_b[co]
  k_gemm_abt<128, 128, 1><<<dim3(16, 4, 16), 256, 0, stream>>>(
      mmat, tht, wbuf, 512, 2048, 256, sMM, sTH, sW, W_b, 1.f);

  k_bnstats<<<512, 256, 0, stream>>>(wbuf, gamma, beta, scale, shift);
  k_final<<<4096, 256, 0, stream>>>(wbuf, x, scale, shift, out);
}